// Round 6
// baseline (329.511 us; speedup 1.0000x reference)
//
#include <hip/hip_runtime.h>
#include <math.h>

#define SS 256
#define HH 256
#define MLEN 1000
#define CWW 16
#define NOC 16
#define RB 24          // ring row stride in bf16 elems (48B, 16B-aligned)

typedef __attribute__((ext_vector_type(8))) short bfrag;
typedef __attribute__((ext_vector_type(4))) float ffrag;
typedef __attribute__((ext_vector_type(16))) float f16v;   // register-resident 16-float value

// float-indexed workspace offsets
#define WS_V2     1048576u
#define WS_STT    1835008u    // sTt bf16 [8][256 h][256 s]
#define WS_WB     2097152u    // packed bf16 weights
#define WS_CCV    2424832u    // [8][256][16]
#define WS_SSV    2457600u
#define WS_CCI    2490368u
#define WS_SSI    2523136u
#define WS_CP     2555904u    // [8][3][256][16]
#define WS_CV     2654208u    // [8][256][16] (dead after k_post -> reused as PSUM)
#define WS_PSUM   2654208u    // [8][1000][4] softmax partial sums (aliases WS_CV)
#define WS_EK     2686976u
#define WS_SK     2689024u
#define WS_ALPHA  2691072u
#define WS_MELI   2691080u
#define WS_TMASK  2691088u

// packed-weight offsets in shorts relative to (unsigned short*)(ws+WS_WB)
#define PK_IN     0u
#define PK_GLU0   65536u
#define PK_GLU1   196608u
#define PK_OUT0   327680u
#define PK_OUT1   393216u
#define PK_P2     458752u

// output offsets
#define OUT_UP    0u
#define OUT_W     2048000u
#define OUT_ALPHA 4096000u
#define OUT_MLEN  4096008u
#define OUT_MMASK 4096016u

__device__ __forceinline__ unsigned bf16rne(float x){
  unsigned u=__float_as_uint(x);
  u += 0x7fffu + ((u>>16)&1u);
  return u;
}
__device__ __forceinline__ unsigned short bf16h(float x){ return (unsigned short)(bf16rne(x)>>16); }
__device__ __forceinline__ float bf2f(unsigned short u){ return __uint_as_float(((unsigned)u)<<16); }
__device__ __forceinline__ int cvtpk(float lo, float hi){
  int r;
  asm("v_cvt_pk_bf16_f32 %0, %1, %2" : "=v"(r) : "v"(lo), "v"(hi));
  return r;
}
__device__ __forceinline__ float fsig(float x){   // sigmoid via v_rcp_f32 (1ulp, bf16-safe)
  return __builtin_amdgcn_rcpf(1.0f+__expf(-x));
}
__device__ __forceinline__ unsigned frag_idx(int k,int n,int KT){
  return (unsigned)(((((n>>4)*KT+(k>>5))*64 + ((k>>3)&3)*16 + (n&15))<<3) + (k&7));
}

// general conv1 path (boundary blocks only) — free function, by-value return, no captures
__device__ __forceinline__ f16v conv1gen_f(int s,int T,int mel,int b,
    const float* __restrict__ ws, const float* __restrict__ cpb,
    const float* __restrict__ mkb1k, const float* __restrict__ mkb1b,
    const float* skL, const float* ekL, const unsigned char* finC){
  f16v acc;
  bool fv=(T>=1)&&(T<=998)&&(T+1<mel);
  bool fi=(T>=2)&&(T<=998)&&(T-1>=mel);
  if(fv||fi){
    acc=*(const f16v*)(ws+(fv?WS_CCV:WS_CCI)+(unsigned)(b*SS+s)*16u)
       +(float)T * *(const f16v*)(ws+(fv?WS_SSV:WS_SSI)+(unsigned)(b*SS+s)*16u);
  } else {
    acc=*(const f16v*)mkb1b;
    #pragma unroll
    for(int dt=0;dt<3;dt++){
      int tr=T+dt-1;
      if(tr<0||tr>=MLEN) continue;
      bool valid=(tr<mel);
      float tt2=(float)(tr+1);
      acc+=*(const f16v*)(cpb+(unsigned)(dt*SS+s)*NOC);
      #pragma unroll
      for(int ds=0;ds<3;ds++){
        int j=s+ds;
        float f=valid?((j>=1&&j<=SS)?1.0f:0.0f):(float)finC[j];
        float gg=f*(tt2-skL[j]);
        float hh=f*(ekL[j]-tt2);
        acc+=gg* *(const f16v*)(mkb1k+(unsigned)(((dt*3+ds)*18+0)*NOC))
            +hh* *(const f16v*)(mkb1k+(unsigned)(((dt*3+ds)*18+1)*NOC));
      }
    }
  }
  return acc;
}

// ---------------- mask canonicalization + weight packing (one launch) ----------------
__global__ __launch_bounds__(256) void k_prepmask(const void* __restrict__ traw,
    const float* __restrict__ in_w,
    const float* __restrict__ g0, const float* __restrict__ g1,
    const float* __restrict__ o0, const float* __restrict__ o1,
    const float* __restrict__ p2k, float* __restrict__ ws){
  int tid=threadIdx.x;
  if(blockIdx.x==256){
    __shared__ int s_fu, s_ff, s_nz;
    const unsigned char* mb=(const unsigned char*)traw;
    const unsigned int*  mw=(const unsigned int*)traw;
    if(tid==0){s_fu=0;s_ff=0;s_nz=0;}
    __syncthreads();
    int fu=0,ff=0,nz=0;
    for(int w=tid;w<512;w+=256){
      unsigned int v=mw[w];
      if(v){ nz=1; if(v==0x3F800000u) ff=1; else if(v&0xFFFFFF00u) fu=1; }
    }
    if(fu) atomicOr(&s_fu,1);
    if(ff) atomicOr(&s_ff,1);
    if(nz) atomicOr(&s_nz,1);
    __syncthreads();
    int words = (s_ff || (!s_fu && s_nz));
    for(int i=tid;i<2048;i+=256){
      unsigned int v = words ? mw[i] : (unsigned int)mb[i];
      ws[WS_TMASK+i] = v ? 1.0f : 0.0f;
    }
    return;
  }
  unsigned short* wb=(unsigned short*)(ws+WS_WB);
  int gid=blockIdx.x*256+tid, stride=65536;
  for(int i=gid;i<65536;i+=stride){ int k=i>>8,n=i&255; wb[PK_IN  +frag_idx(k,n,8)]=bf16h(in_w[i]); }
  for(int i=gid;i<131072;i+=stride){ int k=i>>9,n=i&511; wb[PK_GLU0+frag_idx(k,n,8)]=bf16h(g0[i]); }
  for(int i=gid;i<131072;i+=stride){ int k=i>>9,n=i&511; wb[PK_GLU1+frag_idx(k,n,8)]=bf16h(g1[i]); }
  for(int i=gid;i<65536;i+=stride){ int k=i>>8,n=i&255; wb[PK_OUT0+frag_idx(k,n,8)]=bf16h(o0[i]); }
  for(int i=gid;i<65536;i+=stride){ int k=i>>8,n=i&255; wb[PK_OUT1+frag_idx(k,n,8)]=bf16h(o1[i]); }
  for(int i=gid;i<196608;i+=stride){ int k3=i>>16,r=i&65535,k=r>>8,n=r&255;
    wb[PK_P2+(unsigned)k3*65536u+frag_idx(k,n,8)]=bf16h(p2k[i]); }
}

// ---------------- fused front-end: inproj -> LConv0 -> LConv1 -> V2 ----------------
// 8-row output tile, +-2 halo recompute, all intermediates in LDS.
__global__ __launch_bounds__(256) void k_front(
    const float* __restrict__ ce, const float* __restrict__ spk,
    const unsigned short* __restrict__ wb, const float* __restrict__ in_b,
    const float* __restrict__ g0b, const float* __restrict__ ln0g, const float* __restrict__ ln0b,
    const float* __restrict__ dw0, const float* __restrict__ o0b,
    const float* __restrict__ g1b, const float* __restrict__ ln1g, const float* __restrict__ ln1b,
    const float* __restrict__ dw1, const float* __restrict__ o1b,
    const float* __restrict__ tmask, float* __restrict__ V2){
  __shared__ unsigned short Abf[16][264];
  __shared__ unsigned short Hb[16][264];
  __shared__ float Xf[16][264];
  __shared__ float Vf[16][264];
  __shared__ float dws[2][3][256];
  __shared__ float tmL[20];
  int b=blockIdx.x>>5, tile=blockIdx.x&31, s0=tile*8, tid=threadIdx.x;
  int w=tid>>6, lane=tid&63, lq=lane>>4, lm=lane&15;
  {
    float d0=dw0[tid*3],d1=dw0[tid*3+1],d2=dw0[tid*3+2];
    float mx=fmaxf(d0,fmaxf(d1,d2));
    float e0=__expf(d0-mx),e1=__expf(d1-mx),e2=__expf(d2-mx);
    float inv=1.0f/(e0+e1+e2);
    dws[0][0][tid]=e0*inv; dws[0][1][tid]=e1*inv; dws[0][2][tid]=e2*inv;
    d0=dw1[tid*3];d1=dw1[tid*3+1];d2=dw1[tid*3+2];
    mx=fmaxf(d0,fmaxf(d1,d2));
    e0=__expf(d0-mx);e1=__expf(d1-mx);e2=__expf(d2-mx);
    inv=1.0f/(e0+e1+e2);
    dws[1][0][tid]=e0*inv; dws[1][1][tid]=e1*inv; dws[1][2][tid]=e2*inv;
  }
  if(tid<18){
    int sI=s0-2+tid;
    tmL[tid]=(sI>=0&&sI<256)? tmask[b*256+sI] : 1.0f;
  }
  // phase1: stage concat(ce,spk) rows s0-2..s0+9 as bf16
  for(int it=0;it<16;it++){
    float v=0.f;
    int sI=s0-2+it;
    if(it<12 && sI>=0 && sI<256){
      int m=b*256+sI;
      v=(tid<192)? ce[m*192+tid] : spk[b*64+tid-192];
    }
    Abf[it][tid]=bf16h(v);
  }
  __syncthreads();
  // phase2: inproj MFMA -> Xf (+bias)
  {
    ffrag acc[4];
    #pragma unroll
    for(int j=0;j<4;j++){acc[j][0]=0;acc[j][1]=0;acc[j][2]=0;acc[j][3]=0;}
    #pragma unroll
    for(int kt=0;kt<8;kt++){
      bfrag af=*(const bfrag*)&Abf[lm][kt*32+lq*8];
      #pragma unroll
      for(int j=0;j<4;j++){
        int nt=w*4+j;
        bfrag bf=*(const bfrag*)(wb+PK_IN+((((unsigned)(nt*8+kt))*64u+(unsigned)lane)<<3));
        acc[j]=__builtin_amdgcn_mfma_f32_16x16x32_bf16(af,bf,acc[j],0,0,0);
      }
    }
    #pragma unroll
    for(int j=0;j<4;j++){
      int n=w*64+j*16+lm;
      float bn=in_b[n];
      #pragma unroll
      for(int reg=0;reg<4;reg++) Xf[lq*4+reg][n]=acc[j][reg]+bn;
    }
  }
  __syncthreads();
  // phase3: LN0 -> Abf bf16
  {
    int r=tid>>4, seg=tid&15;
    if(r<12){
      float s=0.f,q=0.f;
      #pragma unroll
      for(int j4=0;j4<4;j4++){
        float4 v=*(const float4*)&Xf[r][seg*16+j4*4];
        s+=v.x+v.y+v.z+v.w; q+=v.x*v.x+v.y*v.y+v.z*v.z+v.w*v.w;
      }
      s+=__shfl_xor(s,1); q+=__shfl_xor(q,1);
      s+=__shfl_xor(s,2); q+=__shfl_xor(q,2);
      s+=__shfl_xor(s,4); q+=__shfl_xor(q,4);
      s+=__shfl_xor(s,8); q+=__shfl_xor(q,8);
      float mean=s*(1.0f/256.0f), rstd=rsqrtf(q*(1.0f/256.0f)-mean*mean+1e-5f);
      #pragma unroll
      for(int j4=0;j4<4;j4++){
        int c=seg*16+j4*4;
        float4 v=*(const float4*)&Xf[r][c];
        int p0=cvtpk((v.x-mean)*rstd*ln0g[c+0]+ln0b[c+0],(v.y-mean)*rstd*ln0g[c+1]+ln0b[c+1]);
        int p1=cvtpk((v.z-mean)*rstd*ln0g[c+2]+ln0b[c+2],(v.w-mean)*rstd*ln0g[c+3]+ln0b[c+3]);
        *(uint2*)&Abf[r][c]=make_uint2((unsigned)p0,(unsigned)p1);
      }
    } else {
      #pragma unroll
      for(int j4=0;j4<4;j4++) *(uint2*)&Abf[r][seg*16+j4*4]=make_uint2(0,0);
    }
  }
  __syncthreads();
  // phase4: glu0 -> Hb (masked)
  {
    ffrag aa[4],ag[4];
    #pragma unroll
    for(int j=0;j<4;j++){aa[j][0]=0;aa[j][1]=0;aa[j][2]=0;aa[j][3]=0;
                         ag[j][0]=0;ag[j][1]=0;ag[j][2]=0;ag[j][3]=0;}
    #pragma unroll
    for(int kt=0;kt<8;kt++){
      bfrag af=*(const bfrag*)&Abf[lm][kt*32+lq*8];
      #pragma unroll
      for(int j=0;j<4;j++){
        int nta=w*4+j, ntg=nta+16;
        bfrag bfa=*(const bfrag*)(wb+PK_GLU0+((((unsigned)(nta*8+kt))*64u+(unsigned)lane)<<3));
        bfrag bfg=*(const bfrag*)(wb+PK_GLU0+((((unsigned)(ntg*8+kt))*64u+(unsigned)lane)<<3));
        aa[j]=__builtin_amdgcn_mfma_f32_16x16x32_bf16(af,bfa,aa[j],0,0,0);
        ag[j]=__builtin_amdgcn_mfma_f32_16x16x32_bf16(af,bfg,ag[j],0,0,0);
      }
    }
    __syncthreads();   // Abf reads done (reused next phase)
    #pragma unroll
    for(int j=0;j<4;j++){
      int n=w*64+j*16+lm;
      float ba=g0b[n], bg=g0b[n+256];
      #pragma unroll
      for(int reg=0;reg<4;reg++){
        int row=lq*4+reg;
        float a=aa[j][reg]+ba, g=ag[j][reg]+bg;
        float hv=a*fsig(g);
        if(row>=12||tmL[row]!=0.0f) hv=0.0f;
        Hb[row][n]=bf16h(hv);
      }
    }
  }
  __syncthreads();
  // phase5: dwconv0 -> Abf rows 0..9
  {
    float w0=dws[0][0][tid],w1=dws[0][1][tid],w2=dws[0][2][tid];
    for(int r=0;r<10;r++){
      float a=w0*bf2f(Hb[r][tid])+w1*bf2f(Hb[r+1][tid])+w2*bf2f(Hb[r+2][tid]);
      Abf[r][tid]=bf16h(a);
    }
    for(int r=10;r<16;r++) Abf[r][tid]=0;
  }
  __syncthreads();
  // phase6: outproj0 + residual + mask -> Vf rows 0..9
  {
    ffrag acc[4];
    #pragma unroll
    for(int j=0;j<4;j++){acc[j][0]=0;acc[j][1]=0;acc[j][2]=0;acc[j][3]=0;}
    #pragma unroll
    for(int kt=0;kt<8;kt++){
      bfrag af=*(const bfrag*)&Abf[lm][kt*32+lq*8];
      #pragma unroll
      for(int j=0;j<4;j++){
        int nt=w*4+j;
        bfrag bf=*(const bfrag*)(wb+PK_OUT0+((((unsigned)(nt*8+kt))*64u+(unsigned)lane)<<3));
        acc[j]=__builtin_amdgcn_mfma_f32_16x16x32_bf16(af,bf,acc[j],0,0,0);
      }
    }
    #pragma unroll
    for(int j=0;j<4;j++){
      int n=w*64+j*16+lm;
      float bn=o0b[n];
      #pragma unroll
      for(int reg=0;reg<4;reg++){
        int row=lq*4+reg;
        float v=(row<10 && tmL[row+1]==0.0f)? acc[j][reg]+bn+Xf[row+1][n] : 0.0f;
        Vf[row][n]=v;
      }
    }
  }
  __syncthreads();
  // phase7: LN1 -> Abf
  {
    int r=tid>>4, seg=tid&15;
    if(r<10){
      float s=0.f,q=0.f;
      #pragma unroll
      for(int j4=0;j4<4;j4++){
        float4 v=*(const float4*)&Vf[r][seg*16+j4*4];
        s+=v.x+v.y+v.z+v.w; q+=v.x*v.x+v.y*v.y+v.z*v.z+v.w*v.w;
      }
      s+=__shfl_xor(s,1); q+=__shfl_xor(q,1);
      s+=__shfl_xor(s,2); q+=__shfl_xor(q,2);
      s+=__shfl_xor(s,4); q+=__shfl_xor(q,4);
      s+=__shfl_xor(s,8); q+=__shfl_xor(q,8);
      float mean=s*(1.0f/256.0f), rstd=rsqrtf(q*(1.0f/256.0f)-mean*mean+1e-5f);
      #pragma unroll
      for(int j4=0;j4<4;j4++){
        int c=seg*16+j4*4;
        float4 v=*(const float4*)&Vf[r][c];
        int p0=cvtpk((v.x-mean)*rstd*ln1g[c+0]+ln1b[c+0],(v.y-mean)*rstd*ln1g[c+1]+ln1b[c+1]);
        int p1=cvtpk((v.z-mean)*rstd*ln1g[c+2]+ln1b[c+2],(v.w-mean)*rstd*ln1g[c+3]+ln1b[c+3]);
        *(uint2*)&Abf[r][c]=make_uint2((unsigned)p0,(unsigned)p1);
      }
    } else {
      #pragma unroll
      for(int j4=0;j4<4;j4++) *(uint2*)&Abf[r][seg*16+j4*4]=make_uint2(0,0);
    }
  }
  __syncthreads();
  // phase8: glu1 -> Hb (masked)
  {
    ffrag aa[4],ag[4];
    #pragma unroll
    for(int j=0;j<4;j++){aa[j][0]=0;aa[j][1]=0;aa[j][2]=0;aa[j][3]=0;
                         ag[j][0]=0;ag[j][1]=0;ag[j][2]=0;ag[j][3]=0;}
    #pragma unroll
    for(int kt=0;kt<8;kt++){
      bfrag af=*(const bfrag*)&Abf[lm][kt*32+lq*8];
      #pragma unroll
      for(int j=0;j<4;j++){
        int nta=w*4+j, ntg=nta+16;
        bfrag bfa=*(const bfrag*)(wb+PK_GLU1+((((unsigned)(nta*8+kt))*64u+(unsigned)lane)<<3));
        bfrag bfg=*(const bfrag*)(wb+PK_GLU1+((((unsigned)(ntg*8+kt))*64u+(unsigned)lane)<<3));
        aa[j]=__builtin_amdgcn_mfma_f32_16x16x32_bf16(af,bfa,aa[j],0,0,0);
        ag[j]=__builtin_amdgcn_mfma_f32_16x16x32_bf16(af,bfg,ag[j],0,0,0);
      }
    }
    __syncthreads();
    #pragma unroll
    for(int j=0;j<4;j++){
      int n=w*64+j*16+lm;
      float ba=g1b[n], bg=g1b[n+256];
      #pragma unroll
      for(int reg=0;reg<4;reg++){
        int row=lq*4+reg;
        float a=aa[j][reg]+ba, g=ag[j][reg]+bg;
        float hv=a*fsig(g);
        if(row>=10||tmL[row+1]!=0.0f) hv=0.0f;
        Hb[row][n]=bf16h(hv);
      }
    }
  }
  __syncthreads();
  // phase9: dwconv1 -> Abf rows 0..7
  {
    float w0=dws[1][0][tid],w1=dws[1][1][tid],w2=dws[1][2][tid];
    for(int r=0;r<8;r++){
      float a=w0*bf2f(Hb[r][tid])+w1*bf2f(Hb[r+1][tid])+w2*bf2f(Hb[r+2][tid]);
      Abf[r][tid]=bf16h(a);
    }
    for(int r=8;r<16;r++) Abf[r][tid]=0;
  }
  __syncthreads();
  // phase10: outproj1 + residual + mask -> V2 global
  {
    ffrag acc[4];
    #pragma unroll
    for(int j=0;j<4;j++){acc[j][0]=0;acc[j][1]=0;acc[j][2]=0;acc[j][3]=0;}
    #pragma unroll
    for(int kt=0;kt<8;kt++){
      bfrag af=*(const bfrag*)&Abf[lm][kt*32+lq*8];
      #pragma unroll
      for(int j=0;j<4;j++){
        int nt=w*4+j;
        bfrag bf=*(const bfrag*)(wb+PK_OUT1+((((unsigned)(nt*8+kt))*64u+(unsigned)lane)<<3));
        acc[j]=__builtin_amdgcn_mfma_f32_16x16x32_bf16(af,bf,acc[j],0,0,0);
      }
    }
    #pragma unroll
    for(int j=0;j<4;j++){
      int n=w*64+j*16+lm;
      float bn=o1b[n];
      #pragma unroll
      for(int reg=0;reg<4;reg++){
        int row=lq*4+reg;
        if(row<8){
          float v=(tmL[row+2]!=0.0f)? 0.0f : acc[j][reg]+bn+Vf[row+1][n];
          V2[(unsigned)(b*256+s0+row)*256u+n]=v;
        }
      }
    }
  }
}

// ---------------- duration head (fp32, exact) ----------------
__global__ __launch_bounds__(256) void k_dur(const float* __restrict__ V2, const float* __restrict__ p1w,
    const float* __restrict__ p1b, const float* __restrict__ sdo, const float* __restrict__ rhythm,
    float* __restrict__ ws, float* __restrict__ outp){
  __shared__ float p1[HH];
  __shared__ float sd[SS];
  __shared__ float red[16];
  int b=blockIdx.x, tid=threadIdx.x;
  int wid=tid>>6, lane=tid&63;
  p1[tid]=p1w[tid];
  __syncthreads();
  float accd=p1b[0];
  const float* row=V2+(unsigned)(b*SS+tid)*HH;
  for(int k=0;k<HH;k+=4){
    float4 v=*(const float4*)&row[k];
    accd+=v.x*p1[k]+v.y*p1[k+1]+v.z*p1[k+2]+v.w*p1[k+3];
  }
  float Dv=fmaxf(accd,0.0f)+log1pf(expf(-fabsf(accd)));
  if(ws[WS_TMASK+b*SS+tid]!=0.0f) Dv=0.0f;
  float sv=sdo[b*SS+tid];
  float a=Dv, c=sv;
  for(int off=32;off;off>>=1){ a+=__shfl_down(a,off); c+=__shfl_down(c,off); }
  if(lane==0){ red[wid]=a; red[wid+8]=c; }
  __syncthreads();
  float Dsum=red[0]+red[1]+red[2]+red[3];
  float pred=red[8]+red[9]+red[10]+red[11];
  float al=(pred/rhythm[b])/Dsum;
  float sDv=al*Dv;
  sd[tid]=sDv;
  __syncthreads();
  for(int off=1;off<SS;off<<=1){
    float t=(tid>=off)?sd[tid-off]:0.0f;
    __syncthreads();
    sd[tid]+=t;
    __syncthreads();
  }
  float ek=sd[tid], sk=ek-sDv;
  ws[WS_EK+b*SS+tid]=ek;
  ws[WS_SK+b*SS+tid]=sk;
  float melf=sd[SS-1];
  int mel=(int)rintf(melf); mel=mel<1?1:(mel>MLEN?MLEN:mel);
  if(tid==0){
    ws[WS_ALPHA+b]=al;
    ((int*)ws)[WS_MELI+b]=mel;
    outp[OUT_ALPHA+b]=al;
    outp[OUT_MLEN+b]=(float)mel;
  }
  for(int t=tid;t<MLEN;t+=SS) outp[OUT_MMASK+b*MLEN+t]=(t>=mel)?1.0f:0.0f;
}

// ---------------- post: T2 (0..255) | cv (256..383) | cp (384..391) ----------------
__global__ __launch_bounds__(256) void k_post(const float* __restrict__ V2,
    const unsigned short* __restrict__ wbp2, const float* __restrict__ p2b,
    const float* __restrict__ cwk, const float* __restrict__ cwb,
    const float* __restrict__ cwg, const float* __restrict__ cwbe,
    const float* __restrict__ mkb1k, const float* __restrict__ mkb1b,
    float* __restrict__ ws){
  int bx=blockIdx.x, tid=threadIdx.x;
  if(bx<256){
    __shared__ unsigned short Abf[18][264];
    int m0=(bx>>1)*16, nh=bx&1, b=m0>>8, s0=m0&255;
    for(int it=0;it<18;it++){
      int sI=s0-1+it;
      float v=(sI>=0&&sI<256)? V2[(unsigned)(b*256+sI)*256u+tid] : 0.0f;
      Abf[it][tid]=bf16h(v);
    }
    __syncthreads();
    int w=tid>>6, lane=tid&63, lq=lane>>4, lm=lane&15;
    ffrag acc[2];
    #pragma unroll
    for(int tt=0;tt<2;tt++){ acc[tt][0]=0;acc[tt][1]=0;acc[tt][2]=0;acc[tt][3]=0; }
    for(int k3=0;k3<3;k3++){
      const unsigned short* wb3=wbp2+(unsigned)k3*65536u;
      #pragma unroll
      for(int kt=0;kt<8;kt++){
        bfrag af=*(const bfrag*)&Abf[lm+k3][kt*32+lq*8];
        #pragma unroll
        for(int tt=0;tt<2;tt++){
          int nt=nh*8+w*2+tt;
          bfrag bf=*(const bfrag*)(wb3+((((unsigned)(nt*8+kt))*64u+(unsigned)lane)<<3));
          acc[tt]=__builtin_amdgcn_mfma_f32_16x16x32_bf16(af,bf,acc[tt],0,0,0);
        }
      }
    }
    float al=ws[WS_ALPHA+b];
    unsigned short* stt=(unsigned short*)(ws+WS_STT);
    #pragma unroll
    for(int tt=0;tt<2;tt++){
      int n=nh*128+w*32+tt*16+lm;
      float bn=p2b[n];
      unsigned short o0=bf16h((acc[tt][0]+bn)*al);
      unsigned short o1=bf16h((acc[tt][1]+bn)*al);
      unsigned short o2=bf16h((acc[tt][2]+bn)*al);
      unsigned short o3=bf16h((acc[tt][3]+bn)*al);
      *(uint2*)&stt[((unsigned)(b*256+n)<<8)+(unsigned)(s0+lq*4)]=
        make_uint2((unsigned)o0|((unsigned)o1<<16),(unsigned)o2|((unsigned)o3<<16));
    }
  } else if(bx<384){
    __shared__ float Vt[18][SS];
    int bb=bx-256;
    int b=bb>>4, tile=bb&15;
    int sbase=tile*16;
    float al=ws[WS_ALPHA+b];
    for(int rr=0;rr<18;rr++){
      int s=sbase-1+rr;
      Vt[rr][tid]=(s>=0&&s<SS)?al*V2[(b*SS+s)*HH+tid]:0.0f;
    }
    __syncthreads();
    int sl=tid>>4, oc=tid&15;
    float a0=cwb[oc],a1=0.f,a2=0.f,a3=0.f;
    for(int k3=0;k3<3;k3++){
      const float* vp=&Vt[sl+k3][0];
      const float* wpp=cwk+(unsigned)k3*HH*CWW+oc;
      for(int c=0;c<HH;c+=4){
        a0+=vp[c+0]*wpp[(c+0)*CWW];
        a1+=vp[c+1]*wpp[(c+1)*CWW];
        a2+=vp[c+2]*wpp[(c+2)*CWW];
        a3+=vp[c+3]*wpp[(c+3)*CWW];
      }
    }
    float acc=fmaxf((a0+a1)+(a2+a3),0.0f);
    float ssum=acc, qsum=acc*acc;
    for(int off=8;off;off>>=1){ ssum+=__shfl_xor(ssum,off); qsum+=__shfl_xor(qsum,off); }
    float mean=ssum*(1.0f/CWW), var=qsum*(1.0f/CWW)-mean*mean;
    float cv=(acc-mean)*rsqrtf(var+1e-5f)*cwg[oc]+cwbe[oc];
    ws[WS_CV+(unsigned)(b*SS+sbase+sl)*CWW+oc]=cv;
  } else {
    __shared__ float CvL[258][17];
    __shared__ float k1c[3][3][CWW][NOC];
    __shared__ float kab[3][3][2][NOC];
    __shared__ float skE[258], ekE[258], fiE[258];
    int b=bx-384;
    for(int i=tid;i<3*3*CWW*NOC;i+=256){
      int oc=i&15, ic=(i>>4)&15, kk=i>>8;
      int kw=kk%3, kh=kk/3;
      k1c[kh][kw][ic][oc]=mkb1k[((kh*3+kw)*18+2+ic)*NOC+oc];
    }
    for(int i=tid;i<3*3*2*NOC;i+=256){
      int oc=i&15, ch=(i>>4)&1, kk=i>>5;
      int kw=kk%3, kh=kk/3;
      kab[kh][kw][ch][oc]=mkb1k[((kh*3+kw)*18+ch)*NOC+oc];
    }
    for(int i=tid;i<SS*CWW;i+=256) CvL[1+(i>>4)][i&15]=ws[WS_CV+(unsigned)b*SS*CWW+i];
    if(tid<CWW){ CvL[0][tid]=0.f; CvL[257][tid]=0.f; }
    if(tid<258){
      float sk=0.f, ek=0.f, fi=0.f;
      if(tid>=1 && tid<=SS){
        sk=ws[WS_SK+b*SS+tid-1];
        ek=ws[WS_EK+b*SS+tid-1];
        fi=(ws[WS_TMASK+b*SS+tid-1]!=0.0f)?0.0f:1.0f;
      }
      skE[tid]=sk; ekE[tid]=ek; fiE[tid]=fi;
    }
    __syncthreads();
    float* cpg=ws+WS_CP+(unsigned)b*3*SS*NOC;
    float ccv[16],ssv[16],cci[16],ssi[16];
    #pragma unroll
    for(int oc=0;oc<NOC;oc++){ float bb2=mkb1b[oc]; ccv[oc]=bb2; cci[oc]=bb2; ssv[oc]=0.f; ssi[oc]=0.f; }
    for(int dt=0;dt<3;dt++){
      float acc[NOC];
      #pragma unroll
      for(int oc=0;oc<NOC;oc++) acc[oc]=0.f;
      #pragma unroll
      for(int ds=0;ds<3;ds++){
        #pragma unroll
        for(int ic=0;ic<CWW;ic++){
          float v=CvL[tid+ds][ic];
          #pragma unroll
          for(int oc=0;oc<NOC;oc++) acc[oc]+=v*k1c[dt][ds][ic][oc];
        }
      }
      for(int oc=0;oc<NOC;oc++) cpg[(unsigned)(dt*SS+tid)*NOC+oc]=acc[oc];
      float va[16],vb[16],ia[16],ib2[16];
      #pragma unroll
      for(int oc=0;oc<NOC;oc++){ va[oc]=0.f; vb[oc]=0.f; ia[oc]=0.f; ib2[oc]=0.f; }
      #pragma unroll
      for(int ds=0;ds<3;ds++){
        int j=tid+ds;
        float inb=(j>=1&&j<=SS)?1.0f:0.0f;
        float fb=fiE[j];
        float skv=skE[j], ekv=ekE[j];
        #pragma unroll
        for(int oc=0;oc<NOC;oc++){
          float ka=kab[dt][ds][0][oc], kb=kab[dt][ds][1][oc];
          float d=ka-kb, e=kb*ekv-ka*skv;
          va[oc]+=inb*d; vb[oc]+=inb*e; ia[oc]+=fb*d; ib2[oc]+=fb*e;
        }
      }
      float dtf=(float)dt;
      #pragma unroll
      for(int oc=0;oc<NOC;oc++){
        ccv[oc]+=acc[oc]+vb[oc]+dtf*va[oc]; ssv[oc]+=va[oc];
        cci[oc]+=acc[oc]+ib2[oc]+dtf*ia[oc]; ssi[oc]+=ia[oc];
      }
    }
    unsigned base=(unsigned)(b*SS+tid)*16u;
    for(int oc=0;oc<NOC;oc++){
      ws[WS_CCV+base+oc]=ccv[oc];
      ws[WS_SSV+base+oc]=ssv[oc];
      ws[WS_CCI+base+oc]=cci[oc];
      ws[WS_SSI+base+oc]=ssi[oc];
    }
  }
}

// pack 16 silu'd values -> 32 bf16 bytes at dst (macro: no captures, no address-taken state)
#define PACK8(ACC, DST) { \
  int q0_=cvtpk((ACC)[0]*fsig((ACC)[0]),(ACC)[1]*fsig((ACC)[1])); \
  int q1_=cvtpk((ACC)[2]*fsig((ACC)[2]),(ACC)[3]*fsig((ACC)[3])); \
  int q2_=cvtpk((ACC)[4]*fsig((ACC)[4]),(ACC)[5]*fsig((ACC)[5])); \
  int q3_=cvtpk((ACC)[6]*fsig((ACC)[6]),(ACC)[7]*fsig((ACC)[7])); \
  int q4_=cvtpk((ACC)[8]*fsig((ACC)[8]),(ACC)[9]*fsig((ACC)[9])); \
  int q5_=cvtpk((ACC)[10]*fsig((ACC)[10]),(ACC)[11]*fsig((ACC)[11])); \
  int q6_=cvtpk((ACC)[12]*fsig((ACC)[12]),(ACC)[13]*fsig((ACC)[13])); \
  int q7_=cvtpk((ACC)[14]*fsig((ACC)[14]),(ACC)[15]*fsig((ACC)[15])); \
  ((int4*)(DST))[0]=make_int4(q0_,q1_,q2_,q3_); \
  ((int4*)(DST))[1]=make_int4(q4_,q5_,q6_,q7_); }

#define PRODUCE(TT) { \
  int T_=(TT); \
  int slot_=((T_%3)+3)%3; \
  short* own_=&ringw[wid][slot_][lane+1][0]; \
  short* hd_=&ringw[wid][slot_][hrow][0]; \
  if((unsigned)T_>=(unsigned)MLEN){ \
    ((int4*)own_)[0]=izero; ((int4*)own_)[1]=izero; \
    if(hl){ ((int4*)hd_)[0]=izero; ((int4*)hd_)[1]=izero; } \
  } else if(pure){ \
    f16v a_=ccR+(float)T_*ssR; \
    PACK8(a_,own_); \
    if(hl){ \
      if(hvalid){ f16v h_=ccH+(float)T_*ssH; PACK8(h_,hd_); } \
      else { ((int4*)hd_)[0]=izero; ((int4*)hd_)[1]=izero; } \
    } \
  } else { \
    f16v a_=conv1gen_f(tid,T_,mel,b,ws,cpb,mkb1k,mkb1b,skL,ekL,finC); \
    PACK8(a_,own_); \
    if(hl){ \
      if(hvalid){ f16v h_=conv1gen_f(hs,T_,mel,b,ws,cpb,mkb1k,mkb1b,skL,ekL,finC); PACK8(h_,hd_); } \
      else { ((int4*)hd_)[0]=izero; ((int4*)hd_)[1]=izero; } \
    } \
  } }

// ---------------- stage B: barrier-free conv1 -> conv2(MFMA) -> e-values + partials ----------------
// Per-wave private ring [3][66][RB]; lanes 0/63 redundantly compute halo rows (bit-identical).
// NO lambdas: PRODUCE macro + free forceinline general path -> all state in registers.
__global__ __launch_bounds__(256,4) void k_stageB(
    float* __restrict__ ws, const float* __restrict__ mkb1k, const float* __restrict__ mkb1b,
    const float* __restrict__ mkb2k, const float* __restrict__ mkb2b,
    const float* __restrict__ lww, const float* __restrict__ lwb,
    float* __restrict__ outp){
  __shared__ __align__(16) short ringw[4][3][66][RB];
  __shared__ float skL[258], ekL[258];
  __shared__ unsigned char finC[260];
  int bx=blockIdx.x, b=bx/125, chunk=bx%125, t0=chunk*8, tid=threadIdx.x;
  int wid=tid>>6, lane=tid&63;
  int lq=lane>>4, lm=lane&15;
  const int4 izero=make_int4(0,0,0,0);
  if(tid<258){
    float sk=0.f, ek=0.f; unsigned char fin=0;
    if(tid>=1 && tid<=SS){
      sk=ws[WS_SK+b*SS+tid-1];
      ek=ws[WS_EK+b*SS+tid-1];
      fin=(ws[WS_TMASK+b*SS+tid-1]!=0.0f)?0:1;
    }
    skL[tid]=sk; ekL[tid]=ek; finC[tid]=fin;
  }
  int mel=((const int*)ws)[WS_MELI+b];
  __syncthreads();   // the only block-wide barrier

  const float* cpb=ws+WS_CP+(unsigned)b*3*SS*NOC;

  unsigned offA[5]; int dtL[5];
  bfrag bfw[5];
  {
    #pragma unroll
    for(int i=0;i<5;i++){
      int g=4*i+lq;
      int dt,ds,hf;
      if(g<18){ dt=g/6; int rm=g-6*dt; ds=rm>>1; hf=rm&1; }
      else { dt=0; ds=0; hf=0; }
      offA[i]=(unsigned)(((lm+ds)*RB+8*hf)*2);   // byte offset within a slot (per-wave ring)
      dtL[i]=dt;
      int pk0,pk1,pk2,pk3;
      if(g<18){
        unsigned u0=bf16rne(mkb2k[(8*g+0)*NOC+lm]), u1=bf16rne(mkb2k[(8*g+1)*NOC+lm]);
        pk0=(int)((u0>>16)|(u1&0xffff0000u));
        u0=bf16rne(mkb2k[(8*g+2)*NOC+lm]); u1=bf16rne(mkb2k[(8*g+3)*NOC+lm]);
        pk1=(int)((u0>>16)|(u1&0xffff0000u));
        u0=bf16rne(mkb2k[(8*g+4)*NOC+lm]); u1=bf16rne(mkb2k[(8*g+5)*NOC+lm]);
        pk2=(int)((u0>>16)|(u1&0xffff0000u));
        u0=bf16rne(mkb2k[(8*g+6)*NOC+lm]); u1=bf16rne(mkb2k[(8*g+7)*NOC+lm]);
        pk3=(int)((u0>>16)|(u1&0xffff0000u));
      } else { pk0=pk1=pk2=pk3=0; }
      bfw[i]=__builtin_bit_cast(bfrag, make_int4(pk0,pk1,pk2,pk3));
    }
  }
  // transposed C: rows = oc (lq*4+reg), cols = s (lm within 16-tile)
  float4 b2q=*(const float4*)&mkb2b[lq*4];
  float4 lw4=*(const float4*)&lww[lq*4];
  float lwb0=lwb[0];

  // halo geometry
  bool hl=(lane==0)||(lane==63);
  int hrow=(lane==0)?0:65;
  int hs=(lane==0)?(wid*64-1):(wid*64+64);
  bool hvalid=hl&&(hs>=0)&&(hs<SS);

  // block classification: the whole T-window [t0-1, t0+8] on one side of mel?
  bool pureV=(t0>=2)&&(t0<=990)&&(t0+9<mel);
  bool pureI=(t0>=3)&&(t0<=990)&&(t0-2>=mel);
  bool pure=pureV||pureI;
  f16v ccR=(f16v)0.f, ssR=(f16v)0.f, ccH=(f16v)0.f, ssH=(f16v)0.f;
  if(pure){
    unsigned co=pureV?WS_CCV:WS_CCI, so=pureV?WS_SSV:WS_SSI;
    ccR=*(const f16v*)(ws+co+(unsigned)(b*SS+tid)*16u);
    ssR=*(const f16v*)(ws+so+(unsigned)(b*SS+tid)*16u);
    if(hvalid){
      ccH=*(const f16v*)(ws+co+(unsigned)(b*SS+hs)*16u);
      ssH=*(const f16v*)(ws+so+(unsigned)(b*SS+hs)*16u);
    }
  }

  PRODUCE(t0-1);
  PRODUCE(t0);
  PRODUCE(t0+1);

  const char* wring=(const char*)&ringw[wid][0][0][0];

  #pragma unroll 1
  for(int r=0;r<8;r++){
    int t=t0+r;
    int tmod=t%3;
    ffrag acc2[4];
    #pragma unroll
    for(int tt=0;tt<4;tt++){ acc2[tt][0]=b2q.x; acc2[tt][1]=b2q.y; acc2[tt][2]=b2q.z; acc2[tt][3]=b2q.w; }
    #pragma unroll
    for(int i=0;i<5;i++){
      int dt=dtL[i];
      int x=tmod+dt+2; x=(x>=3)?x-3:x; x=(x>=3)?x-3:x;
      const char* rp=wring+(unsigned)x*(66u*RB*2u)+offA[i];
      #pragma unroll
      for(int tt=0;tt<4;tt++){
        bfrag a=*(const bfrag*)(rp+tt*(16*RB*2));
        acc2[tt]=__builtin_amdgcn_mfma_f32_16x16x32_bf16(bfw[i],a,acc2[tt],0,0,0);
      }
    }
    // epilogue: silu+lw dot in-lane, exp+mask; one coalesced 256B store per wave
    float esum=0.f, evk=0.f;
    #pragma unroll
    for(int tt=0;tt<4;tt++){
      float pvs=acc2[tt][0]*fsig(acc2[tt][0])*lw4.x
               +acc2[tt][1]*fsig(acc2[tt][1])*lw4.y
               +acc2[tt][2]*fsig(acc2[tt][2])*lw4.z
               +acc2[tt][3]*fsig(acc2[tt][3])*lw4.w;
      pvs+=__shfl_xor(pvs,16);
      pvs+=__shfl_xor(pvs,32);
      int s=wid*64+tt*16+lm;
      float fm=(float)finC[1+s];
      float ev=fm*__expf(pvs+lwb0);     // no-max softmax: logits are O(1)
      if(lq==tt) evk=ev;                // lane keeps its own s=wid*64+lane value
      esum+=ev;
    }
    outp[OUT_W+(unsigned)(b*MLEN+t)*SS+(unsigned)(wid*64+lane)]=evk;
    esum+=__shfl_xor(esum,1);
    esum+=__shfl_xor(esum,2);
    esum+=__shfl_xor(esum,4);
    esum+=__shfl_xor(esum,8);
    if(lane==0) ws[WS_PSUM+(unsigned)(b*MLEN+t)*4u+(unsigned)wid]=esum;
    if(r<7){ PRODUCE(t+2); }            // wave-private ring: no barrier needed
  }
}

// ---------------- up: normalize e -> Wmat (write back) -> W @ sT (MFMA) + LN + mel mask ----------------
__global__ __launch_bounds__(256) void k_up(const float* __restrict__ ws,
    const float* __restrict__ lng, const float* __restrict__ lnb, float* __restrict__ outp){
  __shared__ unsigned short Wbf[16][264];
  __shared__ float UpL[16][264];
  __shared__ float gb[2][256];
  __shared__ float rs[16];
  int bx=blockIdx.x, b=bx/63, tile=bx%63, t0=tile*16, tid=threadIdx.x;
  gb[0][tid]=lng[tid]; gb[1][tid]=lnb[tid];
  if(tid<16){
    int t=t0+tid; float s=0.f;
    if(t<MLEN){
      const float* pp=ws+WS_PSUM+(unsigned)(b*MLEN+t)*4u;
      s=(pp[0]+pp[1])+(pp[2]+pp[3]);
    }
    rs[tid]=(s>0.f)?(1.0f/s):0.0f;
  }
  int mel=((const int*)ws)[WS_MELI+b];
  __syncthreads();
  for(int it=0;it<16;it++){
    int t=t0+it;
    float v=0.f;
    if(t<MLEN){
      float e=outp[OUT_W+(unsigned)(b*MLEN+t)*256u+tid];
      v=e*rs[it];
      outp[OUT_W+(unsigned)(b*MLEN+t)*256u+tid]=v;   // final normalized Wmat
    }
    Wbf[it][tid]=bf16h(v);
  }
  __syncthreads();
  int w=tid>>6, lane=tid&63, lq=lane>>4, lm=lane&15;
  const unsigned short* stt=(const unsigned short*)(ws+WS_STT)+(unsigned)b*65536u;
  ffrag acc[4];
  #pragma unroll
  for(int tt=0;tt<4;tt++){ acc[tt][0]=0;acc[tt][1]=0;acc[tt][2]=0;acc[tt][3]=0; }
  #pragma unroll
  for(int kt=0;kt<8;kt++){
    bfrag af=*(const bfrag*)&Wbf[lm][kt*32+lq*8];
    #pragma unroll
    for(int tt=0;tt<4;tt++){
      int n=w*64+tt*16+lm;
      bfrag bf=*(const bfrag*)(stt+((unsigned)n<<8)+(unsigned)(kt*32+lq*8));
      acc[tt]=__builtin_amdgcn_mfma_f32_16x16x32_bf16(af,bf,acc[tt],0,0,0);
    }
  }
  #pragma unroll
  for(int tt=0;tt<4;tt++){
    #pragma unroll
    for(int reg=0;reg<4;reg++)
      UpL[lq*4+reg][w*64+tt*16+lm]=acc[tt][reg];
  }
  __syncthreads();
  int r=tid>>4, seg=tid&15;
  float s=0.f,q=0.f;
  #pragma unroll
  for(int j4=0;j4<4;j4++){
    float4 v=*(const float4*)&UpL[r][seg*16+j4*4];
    s+=v.x+v.y+v.z+v.w; q+=v.x*v.x+v.y*v.y+v.z*v.z+v.w*v.w;
  }
  s+=__shfl_xor(s,1); q+=__shfl_xor(q,1);
  s+=__shfl_xor(s,2); q+=__shfl_xor(q,2);
  s+=__shfl_xor(s,4); q+=__shfl_xor(q,4);
  s+=__shfl_xor(s,8); q+=__shfl_xor(q,8);
  float mean=s*(1.0f/256.0f), rstd=rsqrtf(q*(1.0f/256.0f)-mean*mean+1e-5f);
  int t=t0+r;
  if(t<MLEN){
    bool vld=(t<mel);
    #pragma unroll
    for(int j4=0;j4<4;j4++){
      int c=seg*16+j4*4;
      float4 v=*(const float4*)&UpL[r][c];
      float4 o;
      o.x=vld?((v.x-mean)*rstd*gb[0][c+0]+gb[1][c+0]):0.0f;
      o.y=vld?((v.y-mean)*rstd*gb[0][c+1]+gb[1][c+1]):0.0f;
      o.z=vld?((v.z-mean)*rstd*gb[0][c+2]+gb[1][c+2]):0.0f;
      o.w=vld?((v.w-mean)*rstd*gb[0][c+3]+gb[1][c+3]):0.0f;
      *(float4*)&outp[OUT_UP+(unsigned)(b*MLEN+t)*256u+c]=o;
    }
  }
}

extern "C" void kernel_launch(void* const* d_in, const int* in_sizes, int n_in,
                              void* d_out, int out_size, void* d_ws, size_t ws_size,
                              hipStream_t stream){
  const float* ce   =(const float*)d_in[0];
  const float* spk  =(const float*)d_in[1];
  const float* rhy  =(const float*)d_in[2];
  const float* sdo  =(const float*)d_in[3];
  const void*  tmr  =d_in[4];
  const float* in_w =(const float*)d_in[5];
  const float* in_b =(const float*)d_in[6];
  const float* l0lg =(const float*)d_in[7];
  const float* l0lb =(const float*)d_in[8];
  const float* l0gw =(const float*)d_in[9];
  const float* l0gb =(const float*)d_in[10];
  const float* l0dw =(const float*)d_in[11];
  const float* l0ow =(const float*)d_in[12];
  const float* l0ob =(const float*)d_in[13];
  const float* l1lg =(const float*)d_in[14];
  const float* l1lb =(const float*)d_in[15];
  const float* l1gw =(const float*)d_in[16];
  const float* l1gb =(const float*)d_in[17];
  const float* l1dw =(const float*)d_in[18];
  const float* l1ow =(const float*)d_in[19];
  const float* l1ob =(const float*)d_in[20];
  const float* p1w  =(const float*)d_in[21];
  const float* p1b  =(const float*)d_in[22];
  const float* p2k  =(const float*)d_in[23];
  const float* p2b  =(const float*)d_in[24];
  const float* cwk  =(const float*)d_in[25];
  const float* cwb  =(const float*)d_in[26];
  const float* cwg  =(const float*)d_in[27];
  const float* cwbe =(const float*)d_in[28];
  const float* m1k  =(const float*)d_in[29];
  const float* m1b  =(const float*)d_in[30];
  const float* m2k  =(const float*)d_in[31];
  const float* m2b  =(const float*)d_in[32];
  const float* lww  =(const float*)d_in[33];
  const float* lwbp =(const float*)d_in[34];
  const float* lng  =(const float*)d_in[35];
  const float* lnb  =(const float*)d_in[36];
  float* ws=(float*)d_ws;
  float* outp=(float*)d_out;
  const unsigned short* wbb=(const unsigned short*)(ws+WS_WB);

  k_prepmask<<<257,256,0,stream>>>(tmr, in_w, l0gw, l1gw, l0ow, l1ow, p2k, ws);
  k_front   <<<256,256,0,stream>>>(ce, spk, wbb, in_b,
                                   l0gb, l0lg, l0lb, l0dw, l0ob,
                                   l1gb, l1lg, l1lb, l1dw, l1ob,
                                   ws+WS_TMASK, ws+WS_V2);
  k_dur     <<<8,256,0,stream>>>(ws+WS_V2, p1w, p1b, sdo, rhy, ws, outp);
  k_post    <<<392,256,0,stream>>>(ws+WS_V2, wbb+PK_P2, p2b, cwk, cwb, cwg, cwbe, m1k, m1b, ws);
  k_stageB  <<<1000,256,0,stream>>>(ws, m1k, m1b, m2k, m2b, lww, lwbp, outp);
  k_up      <<<504,256,0,stream>>>(ws, lng, lnb, outp);
}

// Round 7
// 280.967 us; speedup vs baseline: 1.1728x; 1.1728x over previous
//
#include <hip/hip_runtime.h>
#include <math.h>

#define SS 256
#define HH 256
#define MLEN 1000
#define CWW 16
#define NOC 16
#define RB 16          // ring row stride in bf16 elems (32B, 16B-aligned)

typedef __attribute__((ext_vector_type(8))) short bfrag;
typedef __attribute__((ext_vector_type(4))) float ffrag;

// float-indexed workspace offsets
#define WS_V2     1048576u
#define WS_STT    1835008u    // sTt bf16 [8][256 h][256 s]
#define WS_WB     2097152u    // packed bf16 weights
#define WS_CCV    2424832u    // [8][256][16]
#define WS_SSV    2457600u
#define WS_CCI    2490368u
#define WS_SSI    2523136u
#define WS_CP     2555904u    // [8][3][256][16]
#define WS_CV     2654208u    // [8][256][16] (dead after k_post -> reused as PSUM)
#define WS_PSUM   2654208u    // [8][1000][4] softmax partial sums (aliases WS_CV)
#define WS_EK     2686976u
#define WS_SK     2689024u
#define WS_ALPHA  2691072u
#define WS_MELI   2691080u
#define WS_TMASK  2691088u

// packed-weight offsets in shorts relative to (unsigned short*)(ws+WS_WB)
#define PK_IN     0u
#define PK_GLU0   65536u
#define PK_GLU1   196608u
#define PK_OUT0   327680u
#define PK_OUT1   393216u
#define PK_P2     458752u

// output offsets
#define OUT_UP    0u
#define OUT_W     2048000u
#define OUT_ALPHA 4096000u
#define OUT_MLEN  4096008u
#define OUT_MMASK 4096016u

__device__ __forceinline__ unsigned bf16rne(float x){
  unsigned u=__float_as_uint(x);
  u += 0x7fffu + ((u>>16)&1u);
  return u;
}
__device__ __forceinline__ unsigned short bf16h(float x){ return (unsigned short)(bf16rne(x)>>16); }
__device__ __forceinline__ float bf2f(unsigned short u){ return __uint_as_float(((unsigned)u)<<16); }
__device__ __forceinline__ int cvtpk(float lo, float hi){
  int r;
  asm("v_cvt_pk_bf16_f32 %0, %1, %2" : "=v"(r) : "v"(lo), "v"(hi));
  return r;
}
__device__ __forceinline__ float fsig(float x){   // sigmoid via v_rcp_f32 (1ulp, bf16-safe)
  return __builtin_amdgcn_rcpf(1.0f+__expf(-x));
}
__device__ __forceinline__ unsigned frag_idx(int k,int n,int KT){
  return (unsigned)(((((n>>4)*KT+(k>>5))*64 + ((k>>3)&3)*16 + (n&15))<<3) + (k&7));
}

// ---------------- mask canonicalization + weight packing (one launch) ----------------
__global__ __launch_bounds__(256) void k_prepmask(const void* __restrict__ traw,
    const float* __restrict__ in_w,
    const float* __restrict__ g0, const float* __restrict__ g1,
    const float* __restrict__ o0, const float* __restrict__ o1,
    const float* __restrict__ p2k, float* __restrict__ ws){
  int tid=threadIdx.x;
  if(blockIdx.x==256){
    __shared__ int s_fu, s_ff, s_nz;
    const unsigned char* mb=(const unsigned char*)traw;
    const unsigned int*  mw=(const unsigned int*)traw;
    if(tid==0){s_fu=0;s_ff=0;s_nz=0;}
    __syncthreads();
    int fu=0,ff=0,nz=0;
    for(int w=tid;w<512;w+=256){
      unsigned int v=mw[w];
      if(v){ nz=1; if(v==0x3F800000u) ff=1; else if(v&0xFFFFFF00u) fu=1; }
    }
    if(fu) atomicOr(&s_fu,1);
    if(ff) atomicOr(&s_ff,1);
    if(nz) atomicOr(&s_nz,1);
    __syncthreads();
    int words = (s_ff || (!s_fu && s_nz));
    for(int i=tid;i<2048;i+=256){
      unsigned int v = words ? mw[i] : (unsigned int)mb[i];
      ws[WS_TMASK+i] = v ? 1.0f : 0.0f;
    }
    return;
  }
  unsigned short* wb=(unsigned short*)(ws+WS_WB);
  int gid=blockIdx.x*256+tid, stride=65536;
  for(int i=gid;i<65536;i+=stride){ int k=i>>8,n=i&255; wb[PK_IN  +frag_idx(k,n,8)]=bf16h(in_w[i]); }
  for(int i=gid;i<131072;i+=stride){ int k=i>>9,n=i&511; wb[PK_GLU0+frag_idx(k,n,8)]=bf16h(g0[i]); }
  for(int i=gid;i<131072;i+=stride){ int k=i>>9,n=i&511; wb[PK_GLU1+frag_idx(k,n,8)]=bf16h(g1[i]); }
  for(int i=gid;i<65536;i+=stride){ int k=i>>8,n=i&255; wb[PK_OUT0+frag_idx(k,n,8)]=bf16h(o0[i]); }
  for(int i=gid;i<65536;i+=stride){ int k=i>>8,n=i&255; wb[PK_OUT1+frag_idx(k,n,8)]=bf16h(o1[i]); }
  for(int i=gid;i<196608;i+=stride){ int k3=i>>16,r=i&65535,k=r>>8,n=r&255;
    wb[PK_P2+(unsigned)k3*65536u+frag_idx(k,n,8)]=bf16h(p2k[i]); }
}

// ---------------- fused front-end: inproj -> LConv0 -> LConv1 -> V2 ----------------
// 8-row output tile, +-2 halo recompute, all intermediates in LDS.
__global__ __launch_bounds__(256) void k_front(
    const float* __restrict__ ce, const float* __restrict__ spk,
    const unsigned short* __restrict__ wb, const float* __restrict__ in_b,
    const float* __restrict__ g0b, const float* __restrict__ ln0g, const float* __restrict__ ln0b,
    const float* __restrict__ dw0, const float* __restrict__ o0b,
    const float* __restrict__ g1b, const float* __restrict__ ln1g, const float* __restrict__ ln1b,
    const float* __restrict__ dw1, const float* __restrict__ o1b,
    const float* __restrict__ tmask, float* __restrict__ V2){
  __shared__ unsigned short Abf[16][264];
  __shared__ unsigned short Hb[16][264];
  __shared__ float Xf[16][264];
  __shared__ float Vf[16][264];
  __shared__ float dws[2][3][256];
  __shared__ float tmL[20];
  int b=blockIdx.x>>5, tile=blockIdx.x&31, s0=tile*8, tid=threadIdx.x;
  int w=tid>>6, lane=tid&63, lq=lane>>4, lm=lane&15;
  {
    float d0=dw0[tid*3],d1=dw0[tid*3+1],d2=dw0[tid*3+2];
    float mx=fmaxf(d0,fmaxf(d1,d2));
    float e0=__expf(d0-mx),e1=__expf(d1-mx),e2=__expf(d2-mx);
    float inv=1.0f/(e0+e1+e2);
    dws[0][0][tid]=e0*inv; dws[0][1][tid]=e1*inv; dws[0][2][tid]=e2*inv;
    d0=dw1[tid*3];d1=dw1[tid*3+1];d2=dw1[tid*3+2];
    mx=fmaxf(d0,fmaxf(d1,d2));
    e0=__expf(d0-mx);e1=__expf(d1-mx);e2=__expf(d2-mx);
    inv=1.0f/(e0+e1+e2);
    dws[1][0][tid]=e0*inv; dws[1][1][tid]=e1*inv; dws[1][2][tid]=e2*inv;
  }
  if(tid<18){
    int sI=s0-2+tid;
    tmL[tid]=(sI>=0&&sI<256)? tmask[b*256+sI] : 1.0f;
  }
  // phase1: stage concat(ce,spk) rows s0-2..s0+9 as bf16
  for(int it=0;it<16;it++){
    float v=0.f;
    int sI=s0-2+it;
    if(it<12 && sI>=0 && sI<256){
      int m=b*256+sI;
      v=(tid<192)? ce[m*192+tid] : spk[b*64+tid-192];
    }
    Abf[it][tid]=bf16h(v);
  }
  __syncthreads();
  // phase2: inproj MFMA -> Xf (+bias)
  {
    ffrag acc[4];
    #pragma unroll
    for(int j=0;j<4;j++){acc[j][0]=0;acc[j][1]=0;acc[j][2]=0;acc[j][3]=0;}
    #pragma unroll
    for(int kt=0;kt<8;kt++){
      bfrag af=*(const bfrag*)&Abf[lm][kt*32+lq*8];
      #pragma unroll
      for(int j=0;j<4;j++){
        int nt=w*4+j;
        bfrag bf=*(const bfrag*)(wb+PK_IN+((((unsigned)(nt*8+kt))*64u+(unsigned)lane)<<3));
        acc[j]=__builtin_amdgcn_mfma_f32_16x16x32_bf16(af,bf,acc[j],0,0,0);
      }
    }
    #pragma unroll
    for(int j=0;j<4;j++){
      int n=w*64+j*16+lm;
      float bn=in_b[n];
      #pragma unroll
      for(int reg=0;reg<4;reg++) Xf[lq*4+reg][n]=acc[j][reg]+bn;
    }
  }
  __syncthreads();
  // phase3: LN0 -> Abf bf16
  {
    int r=tid>>4, seg=tid&15;
    if(r<12){
      float s=0.f,q=0.f;
      #pragma unroll
      for(int j4=0;j4<4;j4++){
        float4 v=*(const float4*)&Xf[r][seg*16+j4*4];
        s+=v.x+v.y+v.z+v.w; q+=v.x*v.x+v.y*v.y+v.z*v.z+v.w*v.w;
      }
      s+=__shfl_xor(s,1); q+=__shfl_xor(q,1);
      s+=__shfl_xor(s,2); q+=__shfl_xor(q,2);
      s+=__shfl_xor(s,4); q+=__shfl_xor(q,4);
      s+=__shfl_xor(s,8); q+=__shfl_xor(q,8);
      float mean=s*(1.0f/256.0f), rstd=rsqrtf(q*(1.0f/256.0f)-mean*mean+1e-5f);
      #pragma unroll
      for(int j4=0;j4<4;j4++){
        int c=seg*16+j4*4;
        float4 v=*(const float4*)&Xf[r][c];
        int p0=cvtpk((v.x-mean)*rstd*ln0g[c+0]+ln0b[c+0],(v.y-mean)*rstd*ln0g[c+1]+ln0b[c+1]);
        int p1=cvtpk((v.z-mean)*rstd*ln0g[c+2]+ln0b[c+2],(v.w-mean)*rstd*ln0g[c+3]+ln0b[c+3]);
        *(uint2*)&Abf[r][c]=make_uint2((unsigned)p0,(unsigned)p1);
      }
    } else {
      #pragma unroll
      for(int j4=0;j4<4;j4++) *(uint2*)&Abf[r][seg*16+j4*4]=make_uint2(0,0);
    }
  }
  __syncthreads();
  // phase4: glu0 -> Hb (masked)
  {
    ffrag aa[4],ag[4];
    #pragma unroll
    for(int j=0;j<4;j++){aa[j][0]=0;aa[j][1]=0;aa[j][2]=0;aa[j][3]=0;
                         ag[j][0]=0;ag[j][1]=0;ag[j][2]=0;ag[j][3]=0;}
    #pragma unroll
    for(int kt=0;kt<8;kt++){
      bfrag af=*(const bfrag*)&Abf[lm][kt*32+lq*8];
      #pragma unroll
      for(int j=0;j<4;j++){
        int nta=w*4+j, ntg=nta+16;
        bfrag bfa=*(const bfrag*)(wb+PK_GLU0+((((unsigned)(nta*8+kt))*64u+(unsigned)lane)<<3));
        bfrag bfg=*(const bfrag*)(wb+PK_GLU0+((((unsigned)(ntg*8+kt))*64u+(unsigned)lane)<<3));
        aa[j]=__builtin_amdgcn_mfma_f32_16x16x32_bf16(af,bfa,aa[j],0,0,0);
        ag[j]=__builtin_amdgcn_mfma_f32_16x16x32_bf16(af,bfg,ag[j],0,0,0);
      }
    }
    __syncthreads();   // Abf reads done (reused next phase)
    #pragma unroll
    for(int j=0;j<4;j++){
      int n=w*64+j*16+lm;
      float ba=g0b[n], bg=g0b[n+256];
      #pragma unroll
      for(int reg=0;reg<4;reg++){
        int row=lq*4+reg;
        float a=aa[j][reg]+ba, g=ag[j][reg]+bg;
        float hv=a*fsig(g);
        if(row>=12||tmL[row]!=0.0f) hv=0.0f;
        Hb[row][n]=bf16h(hv);
      }
    }
  }
  __syncthreads();
  // phase5: dwconv0 -> Abf rows 0..9
  {
    float w0=dws[0][0][tid],w1=dws[0][1][tid],w2=dws[0][2][tid];
    for(int r=0;r<10;r++){
      float a=w0*bf2f(Hb[r][tid])+w1*bf2f(Hb[r+1][tid])+w2*bf2f(Hb[r+2][tid]);
      Abf[r][tid]=bf16h(a);
    }
    for(int r=10;r<16;r++) Abf[r][tid]=0;
  }
  __syncthreads();
  // phase6: outproj0 + residual + mask -> Vf rows 0..9
  {
    ffrag acc[4];
    #pragma unroll
    for(int j=0;j<4;j++){acc[j][0]=0;acc[j][1]=0;acc[j][2]=0;acc[j][3]=0;}
    #pragma unroll
    for(int kt=0;kt<8;kt++){
      bfrag af=*(const bfrag*)&Abf[lm][kt*32+lq*8];
      #pragma unroll
      for(int j=0;j<4;j++){
        int nt=w*4+j;
        bfrag bf=*(const bfrag*)(wb+PK_OUT0+((((unsigned)(nt*8+kt))*64u+(unsigned)lane)<<3));
        acc[j]=__builtin_amdgcn_mfma_f32_16x16x32_bf16(af,bf,acc[j],0,0,0);
      }
    }
    #pragma unroll
    for(int j=0;j<4;j++){
      int n=w*64+j*16+lm;
      float bn=o0b[n];
      #pragma unroll
      for(int reg=0;reg<4;reg++){
        int row=lq*4+reg;
        float v=(row<10 && tmL[row+1]==0.0f)? acc[j][reg]+bn+Xf[row+1][n] : 0.0f;
        Vf[row][n]=v;
      }
    }
  }
  __syncthreads();
  // phase7: LN1 -> Abf
  {
    int r=tid>>4, seg=tid&15;
    if(r<10){
      float s=0.f,q=0.f;
      #pragma unroll
      for(int j4=0;j4<4;j4++){
        float4 v=*(const float4*)&Vf[r][seg*16+j4*4];
        s+=v.x+v.y+v.z+v.w; q+=v.x*v.x+v.y*v.y+v.z*v.z+v.w*v.w;
      }
      s+=__shfl_xor(s,1); q+=__shfl_xor(q,1);
      s+=__shfl_xor(s,2); q+=__shfl_xor(q,2);
      s+=__shfl_xor(s,4); q+=__shfl_xor(q,4);
      s+=__shfl_xor(s,8); q+=__shfl_xor(q,8);
      float mean=s*(1.0f/256.0f), rstd=rsqrtf(q*(1.0f/256.0f)-mean*mean+1e-5f);
      #pragma unroll
      for(int j4=0;j4<4;j4++){
        int c=seg*16+j4*4;
        float4 v=*(const float4*)&Vf[r][c];
        int p0=cvtpk((v.x-mean)*rstd*ln1g[c+0]+ln1b[c+0],(v.y-mean)*rstd*ln1g[c+1]+ln1b[c+1]);
        int p1=cvtpk((v.z-mean)*rstd*ln1g[c+2]+ln1b[c+2],(v.w-mean)*rstd*ln1g[c+3]+ln1b[c+3]);
        *(uint2*)&Abf[r][c]=make_uint2((unsigned)p0,(unsigned)p1);
      }
    } else {
      #pragma unroll
      for(int j4=0;j4<4;j4++) *(uint2*)&Abf[r][seg*16+j4*4]=make_uint2(0,0);
    }
  }
  __syncthreads();
  // phase8: glu1 -> Hb (masked)
  {
    ffrag aa[4],ag[4];
    #pragma unroll
    for(int j=0;j<4;j++){aa[j][0]=0;aa[j][1]=0;aa[j][2]=0;aa[j][3]=0;
                         ag[j][0]=0;ag[j][1]=0;ag[j][2]=0;ag[j][3]=0;}
    #pragma unroll
    for(int kt=0;kt<8;kt++){
      bfrag af=*(const bfrag*)&Abf[lm][kt*32+lq*8];
      #pragma unroll
      for(int j=0;j<4;j++){
        int nta=w*4+j, ntg=nta+16;
        bfrag bfa=*(const bfrag*)(wb+PK_GLU1+((((unsigned)(nta*8+kt))*64u+(unsigned)lane)<<3));
        bfrag bfg=*(const bfrag*)(wb+PK_GLU1+((((unsigned)(ntg*8+kt))*64u+(unsigned)lane)<<3));
        aa[j]=__builtin_amdgcn_mfma_f32_16x16x32_bf16(af,bfa,aa[j],0,0,0);
        ag[j]=__builtin_amdgcn_mfma_f32_16x16x32_bf16(af,bfg,ag[j],0,0,0);
      }
    }
    __syncthreads();
    #pragma unroll
    for(int j=0;j<4;j++){
      int n=w*64+j*16+lm;
      float ba=g1b[n], bg=g1b[n+256];
      #pragma unroll
      for(int reg=0;reg<4;reg++){
        int row=lq*4+reg;
        float a=aa[j][reg]+ba, g=ag[j][reg]+bg;
        float hv=a*fsig(g);
        if(row>=10||tmL[row+1]!=0.0f) hv=0.0f;
        Hb[row][n]=bf16h(hv);
      }
    }
  }
  __syncthreads();
  // phase9: dwconv1 -> Abf rows 0..7
  {
    float w0=dws[1][0][tid],w1=dws[1][1][tid],w2=dws[1][2][tid];
    for(int r=0;r<8;r++){
      float a=w0*bf2f(Hb[r][tid])+w1*bf2f(Hb[r+1][tid])+w2*bf2f(Hb[r+2][tid]);
      Abf[r][tid]=bf16h(a);
    }
    for(int r=8;r<16;r++) Abf[r][tid]=0;
  }
  __syncthreads();
  // phase10: outproj1 + residual + mask -> V2 global
  {
    ffrag acc[4];
    #pragma unroll
    for(int j=0;j<4;j++){acc[j][0]=0;acc[j][1]=0;acc[j][2]=0;acc[j][3]=0;}
    #pragma unroll
    for(int kt=0;kt<8;kt++){
      bfrag af=*(const bfrag*)&Abf[lm][kt*32+lq*8];
      #pragma unroll
      for(int j=0;j<4;j++){
        int nt=w*4+j;
        bfrag bf=*(const bfrag*)(wb+PK_OUT1+((((unsigned)(nt*8+kt))*64u+(unsigned)lane)<<3));
        acc[j]=__builtin_amdgcn_mfma_f32_16x16x32_bf16(af,bf,acc[j],0,0,0);
      }
    }
    #pragma unroll
    for(int j=0;j<4;j++){
      int n=w*64+j*16+lm;
      float bn=o1b[n];
      #pragma unroll
      for(int reg=0;reg<4;reg++){
        int row=lq*4+reg;
        if(row<8){
          float v=(tmL[row+2]!=0.0f)? 0.0f : acc[j][reg]+bn+Vf[row+1][n];
          V2[(unsigned)(b*256+s0+row)*256u+n]=v;
        }
      }
    }
  }
}

// ---------------- duration head (fp32, exact) ----------------
__global__ __launch_bounds__(256) void k_dur(const float* __restrict__ V2, const float* __restrict__ p1w,
    const float* __restrict__ p1b, const float* __restrict__ sdo, const float* __restrict__ rhythm,
    float* __restrict__ ws, float* __restrict__ outp){
  __shared__ float p1[HH];
  __shared__ float sd[SS];
  __shared__ float red[16];
  int b=blockIdx.x, tid=threadIdx.x;
  int wid=tid>>6, lane=tid&63;
  p1[tid]=p1w[tid];
  __syncthreads();
  float accd=p1b[0];
  const float* row=V2+(unsigned)(b*SS+tid)*HH;
  for(int k=0;k<HH;k+=4){
    float4 v=*(const float4*)&row[k];
    accd+=v.x*p1[k]+v.y*p1[k+1]+v.z*p1[k+2]+v.w*p1[k+3];
  }
  float Dv=fmaxf(accd,0.0f)+log1pf(expf(-fabsf(accd)));
  if(ws[WS_TMASK+b*SS+tid]!=0.0f) Dv=0.0f;
  float sv=sdo[b*SS+tid];
  float a=Dv, c=sv;
  for(int off=32;off;off>>=1){ a+=__shfl_down(a,off); c+=__shfl_down(c,off); }
  if(lane==0){ red[wid]=a; red[wid+8]=c; }
  __syncthreads();
  float Dsum=red[0]+red[1]+red[2]+red[3];
  float pred=red[8]+red[9]+red[10]+red[11];
  float al=(pred/rhythm[b])/Dsum;
  float sDv=al*Dv;
  sd[tid]=sDv;
  __syncthreads();
  for(int off=1;off<SS;off<<=1){
    float t=(tid>=off)?sd[tid-off]:0.0f;
    __syncthreads();
    sd[tid]+=t;
    __syncthreads();
  }
  float ek=sd[tid], sk=ek-sDv;
  ws[WS_EK+b*SS+tid]=ek;
  ws[WS_SK+b*SS+tid]=sk;
  float melf=sd[SS-1];
  int mel=(int)rintf(melf); mel=mel<1?1:(mel>MLEN?MLEN:mel);
  if(tid==0){
    ws[WS_ALPHA+b]=al;
    ((int*)ws)[WS_MELI+b]=mel;
    outp[OUT_ALPHA+b]=al;
    outp[OUT_MLEN+b]=(float)mel;
  }
  for(int t=tid;t<MLEN;t+=SS) outp[OUT_MMASK+b*MLEN+t]=(t>=mel)?1.0f:0.0f;
}

// ---------------- post: T2 (0..255) | cv (256..383) | cp (384..391) ----------------
__global__ __launch_bounds__(256) void k_post(const float* __restrict__ V2,
    const unsigned short* __restrict__ wbp2, const float* __restrict__ p2b,
    const float* __restrict__ cwk, const float* __restrict__ cwb,
    const float* __restrict__ cwg, const float* __restrict__ cwbe,
    const float* __restrict__ mkb1k, const float* __restrict__ mkb1b,
    float* __restrict__ ws){
  int bx=blockIdx.x, tid=threadIdx.x;
  if(bx<256){
    __shared__ unsigned short Abf[18][264];
    int m0=(bx>>1)*16, nh=bx&1, b=m0>>8, s0=m0&255;
    for(int it=0;it<18;it++){
      int sI=s0-1+it;
      float v=(sI>=0&&sI<256)? V2[(unsigned)(b*256+sI)*256u+tid] : 0.0f;
      Abf[it][tid]=bf16h(v);
    }
    __syncthreads();
    int w=tid>>6, lane=tid&63, lq=lane>>4, lm=lane&15;
    ffrag acc[2];
    #pragma unroll
    for(int tt=0;tt<2;tt++){ acc[tt][0]=0;acc[tt][1]=0;acc[tt][2]=0;acc[tt][3]=0; }
    for(int k3=0;k3<3;k3++){
      const unsigned short* wb3=wbp2+(unsigned)k3*65536u;
      #pragma unroll
      for(int kt=0;kt<8;kt++){
        bfrag af=*(const bfrag*)&Abf[lm+k3][kt*32+lq*8];
        #pragma unroll
        for(int tt=0;tt<2;tt++){
          int nt=nh*8+w*2+tt;
          bfrag bf=*(const bfrag*)(wb3+((((unsigned)(nt*8+kt))*64u+(unsigned)lane)<<3));
          acc[tt]=__builtin_amdgcn_mfma_f32_16x16x32_bf16(af,bf,acc[tt],0,0,0);
        }
      }
    }
    float al=ws[WS_ALPHA+b];
    unsigned short* stt=(unsigned short*)(ws+WS_STT);
    #pragma unroll
    for(int tt=0;tt<2;tt++){
      int n=nh*128+w*32+tt*16+lm;
      float bn=p2b[n];
      unsigned short o0=bf16h((acc[tt][0]+bn)*al);
      unsigned short o1=bf16h((acc[tt][1]+bn)*al);
      unsigned short o2=bf16h((acc[tt][2]+bn)*al);
      unsigned short o3=bf16h((acc[tt][3]+bn)*al);
      *(uint2*)&stt[((unsigned)(b*256+n)<<8)+(unsigned)(s0+lq*4)]=
        make_uint2((unsigned)o0|((unsigned)o1<<16),(unsigned)o2|((unsigned)o3<<16));
    }
  } else if(bx<384){
    __shared__ float Vt[18][SS];
    int bb=bx-256;
    int b=bb>>4, tile=bb&15;
    int sbase=tile*16;
    float al=ws[WS_ALPHA+b];
    for(int rr=0;rr<18;rr++){
      int s=sbase-1+rr;
      Vt[rr][tid]=(s>=0&&s<SS)?al*V2[(b*SS+s)*HH+tid]:0.0f;
    }
    __syncthreads();
    int sl=tid>>4, oc=tid&15;
    float a0=cwb[oc],a1=0.f,a2=0.f,a3=0.f;
    for(int k3=0;k3<3;k3++){
      const float* vp=&Vt[sl+k3][0];
      const float* wpp=cwk+(unsigned)k3*HH*CWW+oc;
      for(int c=0;c<HH;c+=4){
        a0+=vp[c+0]*wpp[(c+0)*CWW];
        a1+=vp[c+1]*wpp[(c+1)*CWW];
        a2+=vp[c+2]*wpp[(c+2)*CWW];
        a3+=vp[c+3]*wpp[(c+3)*CWW];
      }
    }
    float acc=fmaxf((a0+a1)+(a2+a3),0.0f);
    float ssum=acc, qsum=acc*acc;
    for(int off=8;off;off>>=1){ ssum+=__shfl_xor(ssum,off); qsum+=__shfl_xor(qsum,off); }
    float mean=ssum*(1.0f/CWW), var=qsum*(1.0f/CWW)-mean*mean;
    float cv=(acc-mean)*rsqrtf(var+1e-5f)*cwg[oc]+cwbe[oc];
    ws[WS_CV+(unsigned)(b*SS+sbase+sl)*CWW+oc]=cv;
  } else {
    __shared__ float CvL[258][17];
    __shared__ float k1c[3][3][CWW][NOC];
    __shared__ float kab[3][3][2][NOC];
    __shared__ float skE[258], ekE[258], fiE[258];
    int b=bx-384;
    for(int i=tid;i<3*3*CWW*NOC;i+=256){
      int oc=i&15, ic=(i>>4)&15, kk=i>>8;
      int kw=kk%3, kh=kk/3;
      k1c[kh][kw][ic][oc]=mkb1k[((kh*3+kw)*18+2+ic)*NOC+oc];
    }
    for(int i=tid;i<3*3*2*NOC;i+=256){
      int oc=i&15, ch=(i>>4)&1, kk=i>>5;
      int kw=kk%3, kh=kk/3;
      kab[kh][kw][ch][oc]=mkb1k[((kh*3+kw)*18+ch)*NOC+oc];
    }
    for(int i=tid;i<SS*CWW;i+=256) CvL[1+(i>>4)][i&15]=ws[WS_CV+(unsigned)b*SS*CWW+i];
    if(tid<CWW){ CvL[0][tid]=0.f; CvL[257][tid]=0.f; }
    if(tid<258){
      float sk=0.f, ek=0.f, fi=0.f;
      if(tid>=1 && tid<=SS){
        sk=ws[WS_SK+b*SS+tid-1];
        ek=ws[WS_EK+b*SS+tid-1];
        fi=(ws[WS_TMASK+b*SS+tid-1]!=0.0f)?0.0f:1.0f;
      }
      skE[tid]=sk; ekE[tid]=ek; fiE[tid]=fi;
    }
    __syncthreads();
    float* cpg=ws+WS_CP+(unsigned)b*3*SS*NOC;
    float ccv[16],ssv[16],cci[16],ssi[16];
    #pragma unroll
    for(int oc=0;oc<NOC;oc++){ float bb2=mkb1b[oc]; ccv[oc]=bb2; cci[oc]=bb2; ssv[oc]=0.f; ssi[oc]=0.f; }
    for(int dt=0;dt<3;dt++){
      float acc[NOC];
      #pragma unroll
      for(int oc=0;oc<NOC;oc++) acc[oc]=0.f;
      #pragma unroll
      for(int ds=0;ds<3;ds++){
        #pragma unroll
        for(int ic=0;ic<CWW;ic++){
          float v=CvL[tid+ds][ic];
          #pragma unroll
          for(int oc=0;oc<NOC;oc++) acc[oc]+=v*k1c[dt][ds][ic][oc];
        }
      }
      for(int oc=0;oc<NOC;oc++) cpg[(unsigned)(dt*SS+tid)*NOC+oc]=acc[oc];
      float va[16],vb[16],ia[16],ib2[16];
      #pragma unroll
      for(int oc=0;oc<NOC;oc++){ va[oc]=0.f; vb[oc]=0.f; ia[oc]=0.f; ib2[oc]=0.f; }
      #pragma unroll
      for(int ds=0;ds<3;ds++){
        int j=tid+ds;
        float inb=(j>=1&&j<=SS)?1.0f:0.0f;
        float fb=fiE[j];
        float skv=skE[j], ekv=ekE[j];
        #pragma unroll
        for(int oc=0;oc<NOC;oc++){
          float ka=kab[dt][ds][0][oc], kb=kab[dt][ds][1][oc];
          float d=ka-kb, e=kb*ekv-ka*skv;
          va[oc]+=inb*d; vb[oc]+=inb*e; ia[oc]+=fb*d; ib2[oc]+=fb*e;
        }
      }
      float dtf=(float)dt;
      #pragma unroll
      for(int oc=0;oc<NOC;oc++){
        ccv[oc]+=acc[oc]+vb[oc]+dtf*va[oc]; ssv[oc]+=va[oc];
        cci[oc]+=acc[oc]+ib2[oc]+dtf*ia[oc]; ssi[oc]+=ia[oc];
      }
    }
    unsigned base=(unsigned)(b*SS+tid)*16u;
    for(int oc=0;oc<NOC;oc++){
      ws[WS_CCV+base+oc]=ccv[oc];
      ws[WS_SSV+base+oc]=ssv[oc];
      ws[WS_CCI+base+oc]=cci[oc];
      ws[WS_SSI+base+oc]=ssi[oc];
    }
  }
}

// ---------------- stage B: conv1 -> conv2(MFMA) -> e-values; 4-slot ring, 1 barrier/row ----------------
// Round-2 structure; 4 ring slots make produce(t+2) disjoint from MFMA(t) reads, so the
// second barrier is gone; softmax normalization deferred to k_up (verified in r4-r6).
__global__ __launch_bounds__(256,4) void k_stageB(
    float* __restrict__ ws, const float* __restrict__ mkb1k, const float* __restrict__ mkb1b,
    const float* __restrict__ mkb2k, const float* __restrict__ mkb2b,
    const float* __restrict__ lww, const float* __restrict__ lwb,
    float* __restrict__ outp){
  __shared__ __align__(16) short ringh[4][258][RB];
  __shared__ float skL[258], ekL[258];
  __shared__ unsigned char finC[260];
  int bx=blockIdx.x, b=bx/125, chunk=bx%125, t0=chunk*8, tid=threadIdx.x;
  int wid=tid>>6, lane=tid&63;
  int lq=lane>>4, lm=lane&15;
  if(tid<258){
    float sk=0.f, ek=0.f; unsigned char fin=0;
    if(tid>=1 && tid<=SS){
      sk=ws[WS_SK+b*SS+tid-1];
      ek=ws[WS_EK+b*SS+tid-1];
      fin=(ws[WS_TMASK+b*SS+tid-1]!=0.0f)?0:1;
    }
    skL[tid]=sk; ekL[tid]=ek; finC[tid]=fin;
  }
  if(tid<64){
    int sl=tid>>4, rem=tid&15;
    int row=(rem<8)?0:257, c=(rem&7)*2;
    *(int*)&ringh[sl][row][c]=0;
  }
  int mel=((const int*)ws)[WS_MELI+b];
  __syncthreads();

  const float* cpb=ws+WS_CP+(unsigned)b*3*SS*NOC;

  unsigned offA[5]; int dtL[5];
  bfrag bfw[5];
  {
    #pragma unroll
    for(int i=0;i<5;i++){
      int g=4*i+lq;
      int dt,ds,hf;
      if(g<18){ dt=g/6; int rm=g-6*dt; ds=rm>>1; hf=rm&1; }
      else { dt=0; ds=0; hf=0; }
      int srow=wid*64+lm+ds;
      offA[i]=(unsigned)((srow*RB+8*hf)*2);
      dtL[i]=dt;
      int pk[4];
      if(g<18){
        #pragma unroll
        for(int j=0;j<4;j++){
          unsigned u0=bf16rne(mkb2k[(8*g+2*j)*NOC+lm]);
          unsigned u1=bf16rne(mkb2k[(8*g+2*j+1)*NOC+lm]);
          pk[j]=(int)((u0>>16)|(u1&0xffff0000u));
        }
      } else pk[0]=pk[1]=pk[2]=pk[3]=0;
      bfw[i]=__builtin_bit_cast(bfrag, make_int4(pk[0],pk[1],pk[2],pk[3]));
    }
  }
  // transposed C: rows = oc (lq*4+reg), cols = s (lm within 16-tile)
  float4 b2q=*(const float4*)&mkb2b[lq*4];
  float4 lw4=*(const float4*)&lww[lq*4];
  float lwb0=lwb[0];
  const char* ringB=(const char*)&ringh[0][0][0];

  // block classification: the whole T-window [t0-1, t0+8] on one side of mel?
  bool pureV=(t0>=2)&&(t0<=990)&&(t0+9<mel);
  bool pureI=(t0>=3)&&(t0<=990)&&(t0-2>=mel);
  bool pure=pureV||pureI;
  float ccR[16], ssR[16];
  if(pure){
    const float* cc=ws+(pureV?WS_CCV:WS_CCI)+(unsigned)(b*SS+tid)*16u;
    const float* s2=ws+(pureV?WS_SSV:WS_SSI)+(unsigned)(b*SS+tid)*16u;
    #pragma unroll
    for(int q=0;q<4;q++){
      float4 c4=((const float4*)cc)[q];
      float4 s4=((const float4*)s2)[q];
      ccR[4*q+0]=c4.x; ccR[4*q+1]=c4.y; ccR[4*q+2]=c4.z; ccR[4*q+3]=c4.w;
      ssR[4*q+0]=s4.x; ssR[4*q+1]=s4.y; ssR[4*q+2]=s4.z; ssR[4*q+3]=s4.w;
    }
  }

  auto conv1fast=[&](int T){
    int slot=T&3;                      // T>=1 for pure blocks
    float Tf=(float)T;
    int pk[8];
    #pragma unroll
    for(int j=0;j<8;j++){
      float x0=fmaf(Tf,ssR[2*j+0],ccR[2*j+0]);
      float x1=fmaf(Tf,ssR[2*j+1],ccR[2*j+1]);
      pk[j]=cvtpk(x0*fsig(x0),x1*fsig(x1));
    }
    int4* dst=(int4*)&ringh[slot][tid+1][0];
    dst[0]=make_int4(pk[0],pk[1],pk[2],pk[3]);
    dst[1]=make_int4(pk[4],pk[5],pk[6],pk[7]);
  };

  auto conv1gen=[&](int T){
    int slot=((T%4)+4)%4;
    int4* dst=(int4*)&ringh[slot][tid+1][0];
    if((unsigned)T>=(unsigned)MLEN){
      dst[0]=make_int4(0,0,0,0);
      dst[1]=make_int4(0,0,0,0);
      return;
    }
    int s=tid;
    float acc[NOC];
    bool fv=(T>=1)&&(T<=998)&&(T+1<mel);
    bool fi=(T>=2)&&(T<=998)&&(T-1>=mel);
    if(fv||fi){
      const float* cc=ws+(fv?WS_CCV:WS_CCI)+(unsigned)(b*SS+s)*16u;
      const float* s2=ws+(fv?WS_SSV:WS_SSI)+(unsigned)(b*SS+s)*16u;
      float Tf=(float)T;
      #pragma unroll
      for(int q=0;q<4;q++){
        float4 c4=((const float4*)cc)[q];
        float4 s4=((const float4*)s2)[q];
        acc[4*q+0]=c4.x+Tf*s4.x; acc[4*q+1]=c4.y+Tf*s4.y;
        acc[4*q+2]=c4.z+Tf*s4.z; acc[4*q+3]=c4.w+Tf*s4.w;
      }
    } else {
      #pragma unroll
      for(int oc=0;oc<NOC;oc++) acc[oc]=mkb1b[oc];
      #pragma unroll
      for(int dt=0;dt<3;dt++){
        int tr=T+dt-1;
        if(tr<0||tr>=MLEN) continue;
        bool valid=(tr<mel);
        float tt=(float)(tr+1);
        float gg[3], hh[3];
        #pragma unroll
        for(int ds=0;ds<3;ds++){
          int j=s+ds;
          float f = valid ? ((j>=1&&j<=SS)?1.0f:0.0f) : (float)finC[j];
          gg[ds]=f*(tt-skL[j]);
          hh[ds]=f*(ekL[j]-tt);
        }
        const float* cpr=cpb+(unsigned)(dt*SS+s)*NOC;
        float4 c0=((const float4*)cpr)[0], c1=((const float4*)cpr)[1];
        float4 c2=((const float4*)cpr)[2], c3=((const float4*)cpr)[3];
        acc[0]+=c0.x; acc[1]+=c0.y; acc[2]+=c0.z; acc[3]+=c0.w;
        acc[4]+=c1.x; acc[5]+=c1.y; acc[6]+=c1.z; acc[7]+=c1.w;
        acc[8]+=c2.x; acc[9]+=c2.y; acc[10]+=c2.z; acc[11]+=c2.w;
        acc[12]+=c3.x; acc[13]+=c3.y; acc[14]+=c3.z; acc[15]+=c3.w;
        #pragma unroll
        for(int ds=0;ds<3;ds++){
          const float* kA=mkb1k+((dt*3+ds)*18+0)*NOC;
          const float* kB=mkb1k+((dt*3+ds)*18+1)*NOC;
          #pragma unroll
          for(int oc=0;oc<NOC;oc++) acc[oc]+=gg[ds]*kA[oc]+hh[ds]*kB[oc];
        }
      }
    }
    int pk[8];
    #pragma unroll
    for(int j=0;j<8;j++){
      float x0=acc[2*j], x1=acc[2*j+1];
      pk[j]=cvtpk(x0*fsig(x0),x1*fsig(x1));
    }
    dst[0]=make_int4(pk[0],pk[1],pk[2],pk[3]);
    dst[1]=make_int4(pk[4],pk[5],pk[6],pk[7]);
  };

  if(pure){ conv1fast(t0-1); conv1fast(t0); conv1fast(t0+1); }
  else    { conv1gen (t0-1); conv1gen (t0); conv1gen (t0+1); }
  __syncthreads();

  #pragma unroll 1
  for(int r=0;r<8;r++){
    int t=t0+r;
    // produce(t+2) first: writes slot (t+2)%4, disjoint from MFMA(t)'s {t-1,t,t+1}%4
    if(r<7){ if(pure) conv1fast(t+2); else conv1gen(t+2); }
    int tmod=t&3;
    ffrag acc2[4];
    #pragma unroll
    for(int tt=0;tt<4;tt++){ acc2[tt][0]=b2q.x; acc2[tt][1]=b2q.y; acc2[tt][2]=b2q.z; acc2[tt][3]=b2q.w; }
    #pragma unroll
    for(int i=0;i<5;i++){
      int dt=dtL[i];
      int x=tmod+dt+3; x=(x>=4)?x-4:x; x=(x>=4)?x-4:x;
      const char* rp=ringB+(unsigned)x*(258u*RB*2u)+offA[i];
      #pragma unroll
      for(int tt=0;tt<4;tt++){
        bfrag a=*(const bfrag*)(rp+tt*(16*RB*2));
        acc2[tt]=__builtin_amdgcn_mfma_f32_16x16x32_bf16(bfw[i],a,acc2[tt],0,0,0);
      }
    }
    // epilogue: silu+lw dot in-lane, exp+mask; coalesced e-store + per-wave partial sum
    float esum=0.f, evk=0.f;
    #pragma unroll
    for(int tt=0;tt<4;tt++){
      float pvs=acc2[tt][0]*fsig(acc2[tt][0])*lw4.x
               +acc2[tt][1]*fsig(acc2[tt][1])*lw4.y
               +acc2[tt][2]*fsig(acc2[tt][2])*lw4.z
               +acc2[tt][3]*fsig(acc2[tt][3])*lw4.w;
      pvs+=__shfl_xor(pvs,16);
      pvs+=__shfl_xor(pvs,32);
      int s=wid*64+tt*16+lm;
      float fm=(float)finC[1+s];
      float ev=fm*__expf(pvs+lwb0);     // no-max softmax: logits are O(1)
      if(lq==tt) evk=ev;                // lane keeps its own s=wid*64+lane value
      esum+=ev;
    }
    outp[OUT_W+(unsigned)(b*MLEN+t)*SS+(unsigned)(wid*64+lane)]=evk;
    esum+=__shfl_xor(esum,1);
    esum+=__shfl_xor(esum,2);
    esum+=__shfl_xor(esum,4);
    esum+=__shfl_xor(esum,8);
    if(lane==0) ws[WS_PSUM+(unsigned)(b*MLEN+t)*4u+(unsigned)wid]=esum;
    // single barrier: slot(t+2) visible for MFMA(t+1); orders slot(t+3) writes after MFMA(t) reads
    if(r<7) __syncthreads();
  }
}

// ---------------- up: normalize e -> Wmat (write back) -> W @ sT (MFMA) + LN + mel mask ----------------
__global__ __launch_bounds__(256) void k_up(const float* __restrict__ ws,
    const float* __restrict__ lng, const float* __restrict__ lnb, float* __restrict__ outp){
  __shared__ unsigned short Wbf[16][264];
  __shared__ float UpL[16][264];
  __shared__ float gb[2][256];
  __shared__ float rs[16];
  int bx=blockIdx.x, b=bx/63, tile=bx%63, t0=tile*16, tid=threadIdx.x;
  gb[0][tid]=lng[tid]; gb[1][tid]=lnb[tid];
  if(tid<16){
    int t=t0+tid; float s=0.f;
    if(t<MLEN){
      const float* pp=ws+WS_PSUM+(unsigned)(b*MLEN+t)*4u;
      s=(pp[0]+pp[1])+(pp[2]+pp[3]);
    }
    rs[tid]=(s>0.f)?(1.0f/s):0.0f;
  }
  int mel=((const int*)ws)[WS_MELI+b];
  __syncthreads();
  for(int it=0;it<16;it++){
    int t=t0+it;
    float v=0.f;
    if(t<MLEN){
      float e=outp[OUT_W+(unsigned)(b*MLEN+t)*256u+tid];
      v=e*rs[it];
      outp[OUT_W+(unsigned)(b*MLEN+t)*256u+tid]=v;   // final normalized Wmat
    }
    Wbf[it][tid]=bf16h(v);
  }
  __syncthreads();
  int w=tid>>6, lane=tid&63, lq=lane>>4, lm=lane&15;
  const unsigned short* stt=(const unsigned short*)(ws+WS_STT)+(unsigned)b*65536u;
  ffrag acc[4];
  #pragma unroll
  for(int tt=0;tt<4;tt++){ acc[tt][0]=0;acc[tt][1]=0;acc[tt][2]=0;acc[tt][3]=0; }
  #pragma unroll
  for(int kt=0;kt<8;kt++){
    bfrag af=*(const bfrag*)&Wbf[lm][kt*32+lq*8];
    #pragma unroll
    for(int tt=0;tt<4;tt++){
      int n=w*64+tt*16+lm;
      bfrag bf=*(const bfrag*)(stt+((unsigned)n<<8)+(unsigned)(kt*32+lq*8));
      acc[tt]=__builtin_amdgcn_mfma_f32_16x16x32_bf16(af,bf,acc[tt],0,0,0);
    }
  }
  #pragma unroll
  for(int tt=0;tt<4;tt++){
    #pragma unroll
    for(int reg=0;reg<4;reg++)
      UpL[lq*4+reg][w*64+tt*16+lm]=acc[tt][reg];
  }
  __syncthreads();
  int r=tid>>4, seg=tid&15;
  float s=0.f,q=0.f;
  #pragma unroll
  for(int j4=0;j4<4;j4++){
    float4 v=*(const float4*)&UpL[r][seg*16+j4*4];
    s+=v.x+v.y+v.z+v.w; q+=v.x*v.x+v.y*v.y+v.z*v.z+v.w*v.w;
  }
  s+=__shfl_xor(s,1); q+=__shfl_xor(q,1);
  s+=__shfl_xor(s,2); q+=__shfl_xor(q,2);
  s+=__shfl_xor(s,4); q+=__shfl_xor(q,4);
  s+=__shfl_xor(s,8); q+=__shfl_xor(q,8);
  float mean=s*(1.0f/256.0f), rstd=rsqrtf(q*(1.0f/256.0f)-mean*mean+1e-5f);
  int t=t0+r;
  if(t<MLEN){
    bool vld=(t<mel);
    #pragma unroll
    for(int j4=0;j4<4;j4++){
      int c=seg*16+j4*4;
      float4 v=*(const float4*)&UpL[r][c];
      float4 o;
      o.x=vld?((v.x-mean)*rstd*gb[0][c+0]+gb[1][c+0]):0.0f;
      o.y=vld?((v.y-mean)*rstd*gb[0][c+1]+gb[1][c+1]):0.0f;
      o.z=vld?((v.z-mean)*rstd*gb[0][c+2]+gb[1][c+2]):0.0f;
      o.w=vld?((v.w-mean)*rstd*gb[0][c+3]+gb[1][c+3]):0.0f;
      *(float4*)&outp[OUT_UP+(unsigned)(b*MLEN+t)*256u+c]=o;
    }
  }
}

extern "C" void kernel_launch(void* const* d_in, const int* in_sizes, int n_in,
                              void* d_out, int out_size, void* d_ws, size_t ws_size,
                              hipStream_t stream){
  const float* ce   =(const float*)d_in[0];
  const float* spk  =(const float*)d_in[1];
  const float* rhy  =(const float*)d_in[2];
  const float* sdo  =(const float*)d_in[3];
  const void*  tmr  =d_in[4];
  const float* in_w =(const float*)d_in[5];
  const float* in_b =(const float*)d_in[6];
  const float* l0lg =(const float*)d_in[7];
  const float* l0lb =(const float*)d_in[8];
  const float* l0gw =(const float*)d_in[9];
  const float* l0gb =(const float*)d_in[10];
  const float* l0dw =(const float*)d_in[11];
  const float* l0ow =(const float*)d_in[12];
  const float* l0ob =(const float*)d_in[13];
  const float* l1lg =(const float*)d_in[14];
  const float* l1lb =(const float*)d_in[15];
  const float* l1gw =(const float*)d_in[16];
  const float* l1gb =(const float*)d_in[17];
  const float* l1dw =(const float*)d_in[18];
  const float* l1ow =(const float*)d_in[19];
  const float* l1ob =(const float*)d_in[20];
  const float* p1w  =(const float*)d_in[21];
  const float* p1b  =(const float*)d_in[22];
  const float* p2k  =(const float*)d_in[23];
  const float* p2b  =(const float*)d_in[24];
  const float* cwk  =(const float*)d_in[25];
  const float* cwb  =(const float*)d_in[26];
  const float* cwg  =(const float*)d_in[27];
  const float* cwbe =(const float*)d_in[28];
  const float* m1k  =(const float*)d_in[29];
  const float* m1b  =(const float*)d_in[30];
  const float* m2k  =(const float*)d_in[31];
  const float* m2b  =(const float*)d_in[32];
  const float* lww  =(const float*)d_in[33];
  const float* lwbp =(const float*)d_in[34];
  const float* lng  =(const float*)d_in[35];
  const float* lnb  =(const float*)d_in[36];
  float* ws=(float*)d_ws;
  float* outp=(float*)d_out;
  const unsigned short* wbb=(const unsigned short*)(ws+WS_WB);

  k_prepmask<<<257,256,0,stream>>>(tmr, in_w, l0gw, l1gw, l0ow, l1ow, p2k, ws);
  k_front   <<<256,256,0,stream>>>(ce, spk, wbb, in_b,
                                   l0gb, l0lg, l0lb, l0dw, l0ob,
                                   l1gb, l1lg, l1lb, l1dw, l1ob,
                                   ws+WS_TMASK, ws+WS_V2);
  k_dur     <<<8,256,0,stream>>>(ws+WS_V2, p1w, p1b, sdo, rhy, ws, outp);
  k_post    <<<392,256,0,stream>>>(ws+WS_V2, wbb+PK_P2, p2b, cwk, cwb, cwg, cwbe, m1k, m1b, ws);
  k_stageB  <<<1000,256,0,stream>>>(ws, m1k, m1b, m2k, m2b, lww, lwbp, outp);
  k_up      <<<504,256,0,stream>>>(ws, lng, lnb, outp);
}